// Round 7
// baseline (138.251 us; speedup 1.0000x reference)
//
#include <hip/hip_runtime.h>
#include <math.h>

#define EMBED 384
#define HID 64
#define NE 4
#define TPB 512
#define MT 8                  // tokens per thread
#define JS 8                  // lanes (j-slices) per token group
#define JPT 8                 // hidden units per thread
#define TOKB 512              // tokens per block

// LDS floats: wln[384*64] + w2s[256] + c1s[64] + c2s[64] + part[2*512] + red[8]
#define WLN_F   (EMBED * HID)          // 24576
#define W2_OFF  (WLN_F)                // 256
#define C1_OFF  (W2_OFF + HID * NE)    // 64
#define C2_OFF  (C1_OFF + HID)         // 64
#define PART_OFF (C2_OFF + HID)        // 1024
#define RED_OFF (PART_OFF + 2 * TPB)   // 8
#define SMEM_FLOATS (RED_OFF + 2 * NE)

__global__ void
__attribute__((amdgpu_flat_work_group_size(TPB, TPB), amdgpu_waves_per_eu(1, 2)))
router_main(
    const float* __restrict__ x, const float* __restrict__ lnw,
    const float* __restrict__ lnb, const float* __restrict__ w1,
    const float* __restrict__ w2, float* __restrict__ out,
    float* __restrict__ ws, int ntok)
{
  extern __shared__ float smem[];
  float* wln = smem;
  float* w2s = smem + W2_OFF;
  float* c1s = smem + C1_OFF;
  float* c2s = smem + C2_OFF;
  float* part = smem + PART_OFF;
  float* red = smem + RED_OFF;

  const int tid = (int)threadIdx.x;

  // ---- stage wln = lnw[d] * w1[d][j] into LDS (12 float4 / thread) ----
  {
    const float4* src = reinterpret_cast<const float4*>(w1);
    float4* dst = reinterpret_cast<float4*>(wln);
    #pragma unroll
    for (int k = 0; k < (WLN_F / 4) / TPB; ++k) {
      const int f4 = tid + k * TPB;
      const float sc = lnw[f4 >> 4];          // d = f4/16 (16 float4 per row)
      float4 v = src[f4];
      v.x *= sc; v.y *= sc; v.z *= sc; v.w *= sc;
      dst[f4] = v;
    }
  }
  if (tid < HID * NE / 4) {                   // stage w2 (64 float4)
    reinterpret_cast<float4*>(w2s)[tid] = reinterpret_cast<const float4*>(w2)[tid];
  }
  if (tid < 2 * NE) red[tid] = 0.f;
  __syncthreads();

  // ---- cooperative c1[j] = sum_d wln[d][j]; c2[j] = sum_d lnb[d]*w1[d][j] ----
  {
    const int j = tid & 63;
    const int dpart = tid >> 6;               // 8 parts x 48 d's
    float c1p = 0.f, c2p = 0.f;
    #pragma unroll 8
    for (int k = 0; k < EMBED / 8; ++k) {
      const int d = dpart * (EMBED / 8) + k;
      c1p += wln[d * HID + j];
      c2p = fmaf(lnb[d], w1[d * HID + j], c2p);
    }
    part[dpart * 64 + j] = c1p;
    part[TPB + dpart * 64 + j] = c2p;
  }
  __syncthreads();
  if (tid < HID) {
    float a = 0.f, b = 0.f;
    #pragma unroll
    for (int p = 0; p < 8; ++p) {
      a += part[p * 64 + tid];
      b += part[TPB + p * 64 + tid];
    }
    c1s[tid] = a;
    c2s[tid] = b;
  }
  __syncthreads();

  // ---- token/lane mapping ----
  const int lane = tid & 63;
  const int wv = tid >> 6;                    // 8 waves
  const int tg = lane >> 3;                   // 8 token groups / wave
  const int jg = lane & 7;                    // j-eighth
  const int wbase = (int)blockIdx.x * TOKB + wv * 64;
  const int t0 = wbase + tg * MT;             // this thread's 8 tokens
  const int joff = jg * JPT;

  const float* __restrict__ xrow = x + (size_t)t0 * EMBED;

  // ---- fused single pass: stats + GEMM1 ----
  float acc[MT][JPT];
  #pragma unroll
  for (int m = 0; m < MT; ++m)
    #pragma unroll
    for (int j = 0; j < JPT; ++j) acc[m][j] = 0.f;
  float s[MT], s2[MT];
  #pragma unroll
  for (int m = 0; m < MT; ++m) { s[m] = 0.f; s2[m] = 0.f; }

  #pragma unroll 2
  for (int dq = 0; dq < EMBED / 4; ++dq) {
    const int d = dq * 4;
    float4 xv[MT];
    #pragma unroll
    for (int m = 0; m < MT; ++m)
      xv[m] = *reinterpret_cast<const float4*>(xrow + (size_t)m * EMBED + d);
    #pragma unroll
    for (int m = 0; m < MT; ++m) {
      s[m] += (xv[m].x + xv[m].y) + (xv[m].z + xv[m].w);
      s2[m] = fmaf(xv[m].x, xv[m].x, s2[m]);
      s2[m] = fmaf(xv[m].y, xv[m].y, s2[m]);
      s2[m] = fmaf(xv[m].z, xv[m].z, s2[m]);
      s2[m] = fmaf(xv[m].w, xv[m].w, s2[m]);
    }
    #pragma unroll
    for (int dd = 0; dd < 4; ++dd) {
      const float* wr = wln + (d + dd) * HID + joff;
      float4 wa = *reinterpret_cast<const float4*>(wr);
      float4 wb = *reinterpret_cast<const float4*>(wr + 4);
      #pragma unroll
      for (int m = 0; m < MT; ++m) {
        const float xx = (dd == 0) ? xv[m].x : (dd == 1) ? xv[m].y
                       : (dd == 2) ? xv[m].z : xv[m].w;
        acc[m][0] = fmaf(xx, wa.x, acc[m][0]);
        acc[m][1] = fmaf(xx, wa.y, acc[m][1]);
        acc[m][2] = fmaf(xx, wa.z, acc[m][2]);
        acc[m][3] = fmaf(xx, wa.w, acc[m][3]);
        acc[m][4] = fmaf(xx, wb.x, acc[m][4]);
        acc[m][5] = fmaf(xx, wb.y, acc[m][5]);
        acc[m][6] = fmaf(xx, wb.z, acc[m][6]);
        acc[m][7] = fmaf(xx, wb.w, acc[m][7]);
      }
    }
  }

  // ---- epilogue: LN-correct, GELU, GEMM2 partials ----
  float mu[MT], rstd[MT];
  #pragma unroll
  for (int m = 0; m < MT; ++m) {
    mu[m] = s[m] * (1.f / EMBED);
    const float var = fmaf(-mu[m], mu[m], s2[m] * (1.f / EMBED));
    rstd[m] = rsqrtf(var + 1e-5f);
  }

  float logit[MT][NE];
  #pragma unroll
  for (int m = 0; m < MT; ++m)
    #pragma unroll
    for (int e = 0; e < NE; ++e) logit[m][e] = 0.f;

  #pragma unroll
  for (int jj = 0; jj < JPT; ++jj) {
    const int j = joff + jj;
    const float c1 = c1s[j];
    const float c2 = c2s[j];
    float4 wv = *reinterpret_cast<const float4*>(w2s + j * NE);
    #pragma unroll
    for (int m = 0; m < MT; ++m) {
      const float hid = fmaf(rstd[m], fmaf(-mu[m], c1, acc[m][jj]), c2);
      const float g = 0.5f * hid * (1.f + erff(hid * 0.7071067811865475f));
      logit[m][0] = fmaf(g, wv.x, logit[m][0]);
      logit[m][1] = fmaf(g, wv.y, logit[m][1]);
      logit[m][2] = fmaf(g, wv.z, logit[m][2]);
      logit[m][3] = fmaf(g, wv.w, logit[m][3]);
    }
  }

  // ---- reduce logits across the 8-lane group ----
  #pragma unroll
  for (int m = 0; m < MT; ++m)
    #pragma unroll
    for (int e = 0; e < NE; ++e) {
      logit[m][e] += __shfl_xor(logit[m][e], 1);
      logit[m][e] += __shfl_xor(logit[m][e], 2);
      logit[m][e] += __shfl_xor(logit[m][e], 4);
    }

  // lane jg takes token t0+jg -> mytok == wbase + lane (coalesced)
  float l[NE];
  #pragma unroll
  for (int e = 0; e < NE; ++e) {
    float v = logit[0][e];
    v = (jg == 1) ? logit[1][e] : v;
    v = (jg == 2) ? logit[2][e] : v;
    v = (jg == 3) ? logit[3][e] : v;
    v = (jg == 4) ? logit[4][e] : v;
    v = (jg == 5) ? logit[5][e] : v;
    v = (jg == 6) ? logit[6][e] : v;
    v = (jg == 7) ? logit[7][e] : v;
    l[e] = v * 0.5f;                          // /T, T=2
  }
  const int mytok = wbase + lane;

  const float mx = fmaxf(fmaxf(l[0], l[1]), fmaxf(l[2], l[3]));
  const float e0 = expf(l[0] - mx), e1 = expf(l[1] - mx),
              e2 = expf(l[2] - mx), e3 = expf(l[3] - mx);
  const float inv = 1.f / (e0 + e1 + e2 + e3);
  const float p0 = e0 * inv, p1 = e1 * inv, p2 = e2 * inv, p3 = e3 * inv;

  int best = 0; float bp = p0;
  if (p1 > bp) { bp = p1; best = 1; }
  if (p2 > bp) { bp = p2; best = 2; }
  if (p3 > bp) { bp = p3; best = 3; }

  if (mytok < ntok) {
    *reinterpret_cast<float4*>(out + (size_t)mytok * 4) = make_float4(p0, p1, p2, p3);
    out[(size_t)ntok * 4 + mytok] = (float)best;
    float* o3 = out + (size_t)ntok * 5 + 1 + (size_t)mytok * 4;
    o3[0] = p0; o3[1] = p1; o3[2] = p2; o3[3] = p3;
  }

  // ---- aux reduction: wave -> LDS -> global ----
  float psum[NE] = {p0, p1, p2, p3};
  float pcnt[NE];
  pcnt[0] = (best == 0) ? 1.f : 0.f;
  pcnt[1] = (best == 1) ? 1.f : 0.f;
  pcnt[2] = (best == 2) ? 1.f : 0.f;
  pcnt[3] = (best == 3) ? 1.f : 0.f;

  #pragma unroll
  for (int e = 0; e < NE; ++e) {
    float a = psum[e], c = pcnt[e];
    #pragma unroll
    for (int off = 32; off; off >>= 1) {
      a += __shfl_xor(a, off);
      c += __shfl_xor(c, off);
    }
    if (lane == 0) {
      atomicAdd(&red[e], a);
      atomicAdd(&red[NE + e], c);
    }
  }
  __syncthreads();
  if (tid < 2 * NE) atomicAdd(&ws[tid], red[tid]);
}

__global__ void router_finalize(const float* __restrict__ ws,
                                float* __restrict__ out, int ntok)
{
  if (threadIdx.x == 0 && blockIdx.x == 0) {
    const float invN = 1.f / (float)ntok;
    float aux = 0.f;
    #pragma unroll
    for (int e = 0; e < NE; ++e)
      aux = fmaf(ws[NE + e] * invN, ws[e] * invN, aux);
    out[(size_t)ntok * 5] = (float)NE * aux;
  }
}

extern "C" void kernel_launch(void* const* d_in, const int* in_sizes, int n_in,
                              void* d_out, int out_size, void* d_ws, size_t ws_size,
                              hipStream_t stream) {
  const float* x   = (const float*)d_in[0];
  const float* lnw = (const float*)d_in[1];
  const float* lnb = (const float*)d_in[2];
  const float* w1  = (const float*)d_in[3];
  const float* w2  = (const float*)d_in[4];
  float* out = (float*)d_out;
  float* ws  = (float*)d_ws;

  const int ntok = in_sizes[0] / EMBED;   // 131072

  hipMemsetAsync(d_ws, 0, 2 * NE * sizeof(float), stream);

  const int blocks = (ntok + TOKB - 1) / TOKB;             // 256
  const size_t smem_bytes = SMEM_FLOATS * sizeof(float);   // ~102 KB
  router_main<<<blocks, TPB, smem_bytes, stream>>>(x, lnw, lnb, w1, w2, out, ws, ntok);
  router_finalize<<<1, 64, 0, stream>>>(ws, out, ntok);
}

// Round 8
// 127.113 us; speedup vs baseline: 1.0876x; 1.0876x over previous
//
#include <hip/hip_runtime.h>
#include <math.h>

#define EMBED 384
#define HID 64
#define NE 4
#define TPB 512
#define MT 8                  // tokens per thread
#define JS 8                  // lanes (j-slices) per token group
#define JPT 8                 // hidden units per thread
#define TOKB 512              // tokens per block

// LDS floats: wln[384*64] + w2s[256] + c1s[64] + c2s[64] + part[2*512] + red[8]
#define WLN_F   (EMBED * HID)          // 24576
#define W2_OFF  (WLN_F)                // 256
#define C1_OFF  (W2_OFF + HID * NE)    // 64
#define C2_OFF  (C1_OFF + HID)         // 64
#define PART_OFF (C2_OFF + HID)        // 1024
#define RED_OFF (PART_OFF + 2 * TPB)   // 8
#define SMEM_FLOATS (RED_OFF + 2 * NE)

__global__ void
__attribute__((amdgpu_flat_work_group_size(TPB, TPB), amdgpu_waves_per_eu(2, 2)))
router_main(
    const float* __restrict__ x, const float* __restrict__ lnw,
    const float* __restrict__ lnb, const float* __restrict__ w1,
    const float* __restrict__ w2, float* __restrict__ out,
    float* __restrict__ ws, int ntok)
{
  extern __shared__ float smem[];
  float* wln = smem;
  float* w2s = smem + W2_OFF;
  float* c1s = smem + C1_OFF;
  float* c2s = smem + C2_OFF;
  float* part = smem + PART_OFF;
  float* red = smem + RED_OFF;

  const int tid = (int)threadIdx.x;

  // ---- stage wln = lnw[d] * w1[d][j] into LDS (12 float4 / thread) ----
  {
    const float4* src = reinterpret_cast<const float4*>(w1);
    float4* dst = reinterpret_cast<float4*>(wln);
    #pragma unroll
    for (int k = 0; k < (WLN_F / 4) / TPB; ++k) {
      const int f4 = tid + k * TPB;
      const float sc = lnw[f4 >> 4];          // d = f4/16 (16 float4 per row)
      float4 v = src[f4];
      v.x *= sc; v.y *= sc; v.z *= sc; v.w *= sc;
      dst[f4] = v;
    }
  }
  if (tid < HID * NE / 4) {                   // stage w2 (64 float4)
    reinterpret_cast<float4*>(w2s)[tid] = reinterpret_cast<const float4*>(w2)[tid];
  }
  if (tid < 2 * NE) red[tid] = 0.f;
  __syncthreads();

  // ---- cooperative c1[j] = sum_d wln[d][j]; c2[j] = sum_d lnb[d]*w1[d][j] ----
  {
    const int j = tid & 63;
    const int dpart = tid >> 6;               // 8 parts x 48 d's
    float c1p = 0.f, c2p = 0.f;
    #pragma unroll 8
    for (int k = 0; k < EMBED / 8; ++k) {
      const int d = dpart * (EMBED / 8) + k;
      c1p += wln[d * HID + j];
      c2p = fmaf(lnb[d], w1[d * HID + j], c2p);
    }
    part[dpart * 64 + j] = c1p;
    part[TPB + dpart * 64 + j] = c2p;
  }
  __syncthreads();
  if (tid < HID) {
    float a = 0.f, b = 0.f;
    #pragma unroll
    for (int p = 0; p < 8; ++p) {
      a += part[p * 64 + tid];
      b += part[TPB + p * 64 + tid];
    }
    c1s[tid] = a;
    c2s[tid] = b;
  }
  __syncthreads();

  // ---- token/lane mapping ----
  const int lane = tid & 63;
  const int wv = tid >> 6;                    // 8 waves
  const int tg = lane >> 3;                   // 8 token groups / wave
  const int jg = lane & 7;                    // j-eighth
  const int wbase = (int)blockIdx.x * TOKB + wv * 64;
  const int t0 = wbase + tg * MT;             // this group's 8 tokens
  const int joff = jg * JPT;

  const float* __restrict__ xrow = x + (size_t)t0 * EMBED;
  const float* __restrict__ xown = x + (size_t)(t0 + jg) * EMBED;

  // ---- fused single pass: own-token stats + GEMM1 ----
  float acc[MT][JPT];
  #pragma unroll
  for (int m = 0; m < MT; ++m)
    #pragma unroll
    for (int j = 0; j < JPT; ++j) acc[m][j] = 0.f;
  float s = 0.f, s2 = 0.f;                    // stats for token t0+jg only

  for (int dq = 0; dq < EMBED / 4; ++dq) {
    const int d = dq * 4;

    // own-token stats: one float4 with immediate offsets off a fixed base
    {
      float4 xo = *reinterpret_cast<const float4*>(xown + d);
      s += (xo.x + xo.y) + (xo.z + xo.w);
      s2 = fmaf(xo.x, xo.x, s2);
      s2 = fmaf(xo.y, xo.y, s2);
      s2 = fmaf(xo.z, xo.z, s2);
      s2 = fmaf(xo.w, xo.w, s2);
    }

    // half 0: dd = 0,1
    {
      const float* wr = wln + d * HID + joff;
      float4 wa0 = *reinterpret_cast<const float4*>(wr);
      float4 wa1 = *reinterpret_cast<const float4*>(wr + 4);
      float4 wb0 = *reinterpret_cast<const float4*>(wr + HID);
      float4 wb1 = *reinterpret_cast<const float4*>(wr + HID + 4);
      #pragma unroll
      for (int m = 0; m < MT; ++m) {
        float2 xv = *reinterpret_cast<const float2*>(xrow + (size_t)m * EMBED + d);
        acc[m][0] = fmaf(xv.x, wa0.x, acc[m][0]);
        acc[m][1] = fmaf(xv.x, wa0.y, acc[m][1]);
        acc[m][2] = fmaf(xv.x, wa0.z, acc[m][2]);
        acc[m][3] = fmaf(xv.x, wa0.w, acc[m][3]);
        acc[m][4] = fmaf(xv.x, wa1.x, acc[m][4]);
        acc[m][5] = fmaf(xv.x, wa1.y, acc[m][5]);
        acc[m][6] = fmaf(xv.x, wa1.z, acc[m][6]);
        acc[m][7] = fmaf(xv.x, wa1.w, acc[m][7]);
        acc[m][0] = fmaf(xv.y, wb0.x, acc[m][0]);
        acc[m][1] = fmaf(xv.y, wb0.y, acc[m][1]);
        acc[m][2] = fmaf(xv.y, wb0.z, acc[m][2]);
        acc[m][3] = fmaf(xv.y, wb0.w, acc[m][3]);
        acc[m][4] = fmaf(xv.y, wb1.x, acc[m][4]);
        acc[m][5] = fmaf(xv.y, wb1.y, acc[m][5]);
        acc[m][6] = fmaf(xv.y, wb1.z, acc[m][6]);
        acc[m][7] = fmaf(xv.y, wb1.w, acc[m][7]);
      }
    }
    // half 1: dd = 2,3
    {
      const float* wr = wln + (d + 2) * HID + joff;
      float4 wa0 = *reinterpret_cast<const float4*>(wr);
      float4 wa1 = *reinterpret_cast<const float4*>(wr + 4);
      float4 wb0 = *reinterpret_cast<const float4*>(wr + HID);
      float4 wb1 = *reinterpret_cast<const float4*>(wr + HID + 4);
      #pragma unroll
      for (int m = 0; m < MT; ++m) {
        float2 xv = *reinterpret_cast<const float2*>(xrow + (size_t)m * EMBED + d + 2);
        acc[m][0] = fmaf(xv.x, wa0.x, acc[m][0]);
        acc[m][1] = fmaf(xv.x, wa0.y, acc[m][1]);
        acc[m][2] = fmaf(xv.x, wa0.z, acc[m][2]);
        acc[m][3] = fmaf(xv.x, wa0.w, acc[m][3]);
        acc[m][4] = fmaf(xv.x, wa1.x, acc[m][4]);
        acc[m][5] = fmaf(xv.x, wa1.y, acc[m][5]);
        acc[m][6] = fmaf(xv.x, wa1.z, acc[m][6]);
        acc[m][7] = fmaf(xv.x, wa1.w, acc[m][7]);
        acc[m][0] = fmaf(xv.y, wb0.x, acc[m][0]);
        acc[m][1] = fmaf(xv.y, wb0.y, acc[m][1]);
        acc[m][2] = fmaf(xv.y, wb0.z, acc[m][2]);
        acc[m][3] = fmaf(xv.y, wb0.w, acc[m][3]);
        acc[m][4] = fmaf(xv.y, wb1.x, acc[m][4]);
        acc[m][5] = fmaf(xv.y, wb1.y, acc[m][5]);
        acc[m][6] = fmaf(xv.y, wb1.z, acc[m][6]);
        acc[m][7] = fmaf(xv.y, wb1.w, acc[m][7]);
      }
    }
  }

  // ---- own-token LN stats -> broadcast to group ----
  const float mu_own = s * (1.f / EMBED);
  const float var_own = fmaf(-mu_own, mu_own, s2 * (1.f / EMBED));
  const float rstd_own = rsqrtf(var_own + 1e-5f);

  const int gbase = lane & ~7;                // first lane of this group
  float mu[MT], rstd[MT];
  #pragma unroll
  for (int m = 0; m < MT; ++m) {
    mu[m]   = __shfl(mu_own,   gbase + m);
    rstd[m] = __shfl(rstd_own, gbase + m);
  }

  // ---- epilogue: LN-correct, GELU, GEMM2 partials ----
  float logit[MT][NE];
  #pragma unroll
  for (int m = 0; m < MT; ++m)
    #pragma unroll
    for (int e = 0; e < NE; ++e) logit[m][e] = 0.f;

  #pragma unroll
  for (int jj = 0; jj < JPT; ++jj) {
    const int j = joff + jj;
    const float c1 = c1s[j];
    const float c2 = c2s[j];
    float4 wv = *reinterpret_cast<const float4*>(w2s + j * NE);
    #pragma unroll
    for (int m = 0; m < MT; ++m) {
      const float hid = fmaf(rstd[m], fmaf(-mu[m], c1, acc[m][jj]), c2);
      const float g = 0.5f * hid * (1.f + erff(hid * 0.7071067811865475f));
      logit[m][0] = fmaf(g, wv.x, logit[m][0]);
      logit[m][1] = fmaf(g, wv.y, logit[m][1]);
      logit[m][2] = fmaf(g, wv.z, logit[m][2]);
      logit[m][3] = fmaf(g, wv.w, logit[m][3]);
    }
  }

  // ---- reduce logits across the 8-lane group ----
  #pragma unroll
  for (int m = 0; m < MT; ++m)
    #pragma unroll
    for (int e = 0; e < NE; ++e) {
      logit[m][e] += __shfl_xor(logit[m][e], 1);
      logit[m][e] += __shfl_xor(logit[m][e], 2);
      logit[m][e] += __shfl_xor(logit[m][e], 4);
    }

  // lane jg takes token t0+jg -> mytok == wbase + lane (coalesced)
  float l[NE];
  #pragma unroll
  for (int e = 0; e < NE; ++e) {
    float v = logit[0][e];
    v = (jg == 1) ? logit[1][e] : v;
    v = (jg == 2) ? logit[2][e] : v;
    v = (jg == 3) ? logit[3][e] : v;
    v = (jg == 4) ? logit[4][e] : v;
    v = (jg == 5) ? logit[5][e] : v;
    v = (jg == 6) ? logit[6][e] : v;
    v = (jg == 7) ? logit[7][e] : v;
    l[e] = v * 0.5f;                          // /T, T=2
  }
  const int mytok = wbase + lane;

  const float mx = fmaxf(fmaxf(l[0], l[1]), fmaxf(l[2], l[3]));
  const float e0 = expf(l[0] - mx), e1 = expf(l[1] - mx),
              e2 = expf(l[2] - mx), e3 = expf(l[3] - mx);
  const float inv = 1.f / (e0 + e1 + e2 + e3);
  const float p0 = e0 * inv, p1 = e1 * inv, p2 = e2 * inv, p3 = e3 * inv;

  int best = 0; float bp = p0;
  if (p1 > bp) { bp = p1; best = 1; }
  if (p2 > bp) { bp = p2; best = 2; }
  if (p3 > bp) { bp = p3; best = 3; }

  if (mytok < ntok) {
    *reinterpret_cast<float4*>(out + (size_t)mytok * 4) = make_float4(p0, p1, p2, p3);
    out[(size_t)ntok * 4 + mytok] = (float)best;
    float* o3 = out + (size_t)ntok * 5 + 1 + (size_t)mytok * 4;
    o3[0] = p0; o3[1] = p1; o3[2] = p2; o3[3] = p3;
  }

  // ---- aux reduction: wave -> LDS -> global ----
  float psum[NE] = {p0, p1, p2, p3};
  float pcnt[NE];
  pcnt[0] = (best == 0) ? 1.f : 0.f;
  pcnt[1] = (best == 1) ? 1.f : 0.f;
  pcnt[2] = (best == 2) ? 1.f : 0.f;
  pcnt[3] = (best == 3) ? 1.f : 0.f;

  #pragma unroll
  for (int e = 0; e < NE; ++e) {
    float a = psum[e], c = pcnt[e];
    #pragma unroll
    for (int off = 32; off; off >>= 1) {
      a += __shfl_xor(a, off);
      c += __shfl_xor(c, off);
    }
    if (lane == 0) {
      atomicAdd(&red[e], a);
      atomicAdd(&red[NE + e], c);
    }
  }
  __syncthreads();
  if (tid < 2 * NE) atomicAdd(&ws[tid], red[tid]);
}

__global__ void router_finalize(const float* __restrict__ ws,
                                float* __restrict__ out, int ntok)
{
  if (threadIdx.x == 0 && blockIdx.x == 0) {
    const float invN = 1.f / (float)ntok;
    float aux = 0.f;
    #pragma unroll
    for (int e = 0; e < NE; ++e)
      aux = fmaf(ws[NE + e] * invN, ws[e] * invN, aux);
    out[(size_t)ntok * 5] = (float)NE * aux;
  }
}

extern "C" void kernel_launch(void* const* d_in, const int* in_sizes, int n_in,
                              void* d_out, int out_size, void* d_ws, size_t ws_size,
                              hipStream_t stream) {
  const float* x   = (const float*)d_in[0];
  const float* lnw = (const float*)d_in[1];
  const float* lnb = (const float*)d_in[2];
  const float* w1  = (const float*)d_in[3];
  const float* w2  = (const float*)d_in[4];
  float* out = (float*)d_out;
  float* ws  = (float*)d_ws;

  const int ntok = in_sizes[0] / EMBED;   // 131072

  hipMemsetAsync(d_ws, 0, 2 * NE * sizeof(float), stream);

  const int blocks = (ntok + TOKB - 1) / TOKB;             // 256
  const size_t smem_bytes = SMEM_FLOATS * sizeof(float);   // ~102 KB
  router_main<<<blocks, TPB, smem_bytes, stream>>>(x, lnw, lnb, w1, w2, out, ws, ntok);
  router_finalize<<<1, 64, 0, stream>>>(ws, out, ntok);
}